// Round 7
// baseline (436.765 us; speedup 1.0000x reference)
//
#include <hip/hip_runtime.h>
#include <hip/hip_cooperative_groups.h>
#include <stdint.h>

// B=32, C=256, P=2 pods, 64x64 spatial (pos=4096). f32 I/O, bf16 MFMA inside.
// R11: cooperative fused kernel, grid 256x512 (1 block/CU guaranteed — R10's
//   512-block coop launch was rejected, output stayed zero => absmax==max|ref|).
//   launch_bounds(512,2) -> VGPR cap 256 (less spill). Units: 4/8/4 per block.
//   Runtime FALLBACK: if hipLaunchCooperativeKernel errors, launch the proven
//   R8 3-kernel path (334 us) instead — round cannot zero out again.
// Phase bodies byte-identical to R8 k_fwd / R9 k_gemm / R5 k_inv -> absmax
// must stay exactly 0.0625.
// d_out slot map (16 KiB per img): lo 8 KiB = f6, hi 8 KiB = F via Faddr().

namespace cgrp = cooperative_groups;

typedef __attribute__((ext_vector_type(4))) float f32x4_t;
typedef __attribute__((ext_vector_type(8))) __bf16 bf16x8_t;
typedef __attribute__((ext_vector_type(8))) unsigned short u16x8_t;
typedef __attribute__((ext_vector_type(4))) unsigned short u16x4_t;
typedef __attribute__((ext_vector_type(4))) unsigned int u32x4_t;

__device__ __forceinline__ float bf2f(unsigned short u) {
  union { unsigned int i; float f; } x; x.i = ((unsigned int)u) << 16; return x.f;
}
__device__ __forceinline__ unsigned short f2bf(float f) {   // RNE
  union { float f; unsigned int i; } x; x.f = f;
  unsigned int i = x.i;
  return (unsigned short)((i + 0x7FFFu + ((i >> 16) & 1u)) >> 16);
}
__device__ __forceinline__ unsigned short f2bf_t(float f) { // truncate (staging)
  union { float f; unsigned int i; } x; x.f = f;
  return (unsigned short)(x.i >> 16);
}
// linear u16 index into F -> physical u16 offset in d_out (slot upper halves)
__device__ __forceinline__ size_t Faddr(size_t f) {
  return ((f >> 12) << 13) + 4096 + (f & 4095);
}

// ======================= fused cooperative kernel =======================
__global__ __launch_bounds__(512, 2) void k_fused(
    const float* __restrict__ x, const float* __restrict__ Wf,
    const float* __restrict__ vv, const float* __restrict__ TT,
    unsigned short* __restrict__ obuf) {
  __shared__ unsigned short smem[36864];       // 72 KiB, reused by all phases
  cgrp::grid_group gg = cgrp::this_grid();
  const int tid = threadIdx.x;
  const int lane = tid & 63, wave = tid >> 6;
  const int quad = lane >> 4, l15 = lane & 15;
  const int bid = blockIdx.x;

  // ================= Phase 1: forward 2D WHT (R8 body, 4 units) =================
  {
    bf16x8_t hf[2][4];
#pragma unroll
    for (int kc = 0; kc < 2; kc++)
#pragma unroll
      for (int t = 0; t < 4; t++) {
        bf16x8_t h;
#pragma unroll
        for (int j = 0; j < 8; j++) {
          int k = kc * 32 + quad * 8 + j, n = t * 16 + l15;
          h[j] = (__builtin_popcount(k & n) & 1) ? (__bf16)-1.0f : (__bf16)1.0f;
        }
        hf[kc][t] = h;
      }

    for (int j = 0; j < 4; ++j) {
      __syncthreads();                         // smem reuse between units
      int u = bid + j * 256;                   // 0..1023
      int cgi = u & 31, b = u >> 5;
      size_t img = (size_t)b * 256 + cgi * 8 + wave;
      unsigned short* T1t = smem + wave * 4608;  // per-wave [64][72] u16 tile

      const float* xim = x + img * 4096;
#pragma unroll
      for (int l = 0; l < 16; l++) {
        int e = (l * 64 + lane) * 4;
        f32x4_t sv = *(const f32x4_t*)(xim + e);
        u16x4_t uu;
#pragma unroll
        for (int jj = 0; jj < 4; jj++) uu[jj] = f2bf_t(sv[jj]);
        int row = e >> 6, col = e & 63;
        *(u16x4_t*)&T1t[row * 72 + col] = uu;
      }

      bf16x8_t xa[4][2];
#pragma unroll
      for (int mt = 0; mt < 4; mt++)
#pragma unroll
        for (int kc = 0; kc < 2; kc++)
          xa[mt][kc] = *(const bf16x8_t*)&T1t[(mt * 16 + l15) * 72 + kc * 32 + quad * 8];

      // GEMM1: T1 = X*H, strip-mined by nt; store transposed [kw][h] into T1t
#pragma unroll
      for (int nt = 0; nt < 4; nt++) {
        f32x4_t a1c[4];
#pragma unroll
        for (int mt = 0; mt < 4; mt++) a1c[mt] = (f32x4_t){0.f, 0.f, 0.f, 0.f};
#pragma unroll
        for (int kc = 0; kc < 2; kc++)
#pragma unroll
          for (int mt = 0; mt < 4; mt++)
            a1c[mt] = __builtin_amdgcn_mfma_f32_16x16x32_bf16(xa[mt][kc], hf[kc][nt], a1c[mt], 0, 0, 0);
#pragma unroll
        for (int mt = 0; mt < 4; mt++) {
          u16x4_t t4;
#pragma unroll
          for (int r = 0; r < 4; r++) t4[r] = f2bf_t(a1c[mt][r]);
          *(u16x4_t*)&T1t[(nt * 16 + l15) * 72 + mt * 16 + quad * 4] = t4;
        }
      }

      // GEMM2: f2 = H*T1
      f32x4_t acc[4][4];
#pragma unroll
      for (int mt = 0; mt < 4; mt++)
#pragma unroll
        for (int nt = 0; nt < 4; nt++) acc[mt][nt] = (f32x4_t){0.f, 0.f, 0.f, 0.f};
#pragma unroll
      for (int kc = 0; kc < 2; kc++)
#pragma unroll
        for (int nt = 0; nt < 4; nt++) {
          bf16x8_t bfr = *(bf16x8_t*)&T1t[(nt * 16 + l15) * 72 + kc * 32 + quad * 8];
#pragma unroll
          for (int mt = 0; mt < 4; mt++)
            acc[mt][nt] = __builtin_amdgcn_mfma_f32_16x16x32_bf16(hf[kc][mt], bfr, acc[mt][nt], 0, 0, 0);
        }

      __syncthreads();                         // all T1t reads done before overlay
      // repack slot = wave^(quad<<1): 2-way bank = free; perm is f(pos)
#pragma unroll
      for (int mt = 0; mt < 4; mt++)
#pragma unroll
        for (int nt = 0; nt < 4; nt++)
#pragma unroll
          for (int r = 0; r < 4; r++) {
            int pos = (mt * 16 + quad * 4 + r) * 64 + nt * 16 + l15;  // kh*64+kw
            smem[pos * 8 + (wave ^ (quad << 1))] = f2bf(acc[mt][nt][r]);
          }
      __syncthreads();
      size_t fbase = ((size_t)b * 32 + cgi) * 4096;
      int hb = wave >> 2;                      // 0 or 1
      if (hb) {
#pragma unroll
        for (int i = 0; i < 8; i++) {
          int pos = i * 512 + tid;
          u32x4_t c = *(u32x4_t*)&smem[pos * 8];
          const int q = (2 * i + 1) & 3;
          u32x4_t o;
          o[0] = c[0 ^ q]; o[1] = c[1 ^ q]; o[2] = c[2 ^ q]; o[3] = c[3 ^ q];
          *(u32x4_t*)(obuf + Faddr((fbase + pos) * 8)) = o;
        }
      } else {
#pragma unroll
        for (int i = 0; i < 8; i++) {
          int pos = i * 512 + tid;
          u32x4_t c = *(u32x4_t*)&smem[pos * 8];
          const int q = (2 * i) & 3;
          u32x4_t o;
          o[0] = c[0 ^ q]; o[1] = c[1 ^ q]; o[2] = c[2 ^ q]; o[3] = c[3 ^ q];
          *(u32x4_t*)(obuf + Faddr((fbase + pos) * 8)) = o;
        }
      }
    }
  }

  gg.sync();                                   // F fully written, device-visible

  // ============ Phase 2: Wcat @ F + soft-threshold (R9 body, 8 units) ============
  {
    const int wm = wave & 3, wn = wave >> 2;
    for (int j = 0; j < 8; ++j) {
      __syncthreads();                         // smem reuse between units
      int u = bid + j * 256;                   // 0..2047
      int n0 = (u & 31) * 128;                 // pos tile
      int m0 = ((u >> 5) & 1) * 256;           // Wcat row tile (m=2o+p)
      int b  = u >> 6;

      f32x4_t acc[4][4];
#pragma unroll
      for (int mt = 0; mt < 4; mt++)
#pragma unroll
        for (int nt = 0; nt < 4; nt++) acc[mt][nt] = (f32x4_t){0.f, 0.f, 0.f, 0.f};

      auto issueB = [&](int ks, int buf) {     // 2x global_load_lds dwordx4, linear dest
        unsigned short* Bl = smem + 16384 + buf * 8192;
#pragma unroll
        for (int i = 0; i < 2; i++) {
          int idx = i * 512 + tid;             // 1024 chunks = 8 cch x 128 r
          int r = idx & 127, cch = idx >> 7;
          size_t f = (((size_t)b * 32 + ks * 8 + cch) * 4096 + n0 + r) * 8;
          const unsigned short* src = obuf + Faddr(f);
          __builtin_amdgcn_global_load_lds(
              (const __attribute__((address_space(1))) void*)src,
              (__attribute__((address_space(3))) void*)(Bl + idx * 8), 16, 0, 0);
        }
      };
      auto fetchA = [&](int ks, f32x4_t (&ar)[4][2]) {  // gch-swizzled coalesced fetch
        int k0 = ks * 64;
#pragma unroll
        for (int i = 0; i < 4; i++) {
          int idx = i * 512 + tid;             // 2048 chunks = 256 rows x 8 ch
          int r = idx >> 3, cch = idx & 7;
          int gch = cch ^ (r & 7);
          int m = m0 + r;
          const float* wp = Wf + ((m & 1) << 16) + ((m >> 1) << 8) + k0 + gch * 8;
          ar[i][0] = *(const f32x4_t*)wp;
          ar[i][1] = *(const f32x4_t*)(wp + 4);
        }
      };
      auto writeA = [&](f32x4_t (&ar)[4][2]) { // convert + LINEAR store (0-conflict)
#pragma unroll
        for (int i = 0; i < 4; i++) {
          int idx = i * 512 + tid;
          u16x8_t uu;
#pragma unroll
          for (int jj = 0; jj < 4; jj++) { uu[jj] = f2bf_t(ar[i][0][jj]); uu[4 + jj] = f2bf_t(ar[i][1][jj]); }
          *(u16x8_t*)&smem[idx * 8] = uu;      // slot cch of row r holds gch=cch^(r&7)
        }
      };

      f32x4_t areg[4][2];
      issueB(0, 0);
      fetchA(0, areg);
      writeA(areg);
      __syncthreads();                         // drains vmcnt: B(0)+A(0) ready

      for (int ks = 0; ks < 4; ++ks) {
        int p = ks & 1;
        if (ks < 3) {
          issueB(ks + 1, p ^ 1);
          fetchA(ks + 1, areg);
        }
        unsigned short* Bl = smem + 16384 + p * 8192;
#pragma unroll
        for (int kk = 0; kk < 2; ++kk) {
          bf16x8_t af[4], bfr[4];
#pragma unroll
          for (int mt = 0; mt < 4; mt++) {
            int row = wm * 64 + mt * 16 + l15; // 0..255
            int s = (kk * 4 + quad) ^ (row & 7);
            af[mt] = *(const bf16x8_t*)&smem[row * 64 + s * 8];
          }
          int ch = kk * 4 + quad;
#pragma unroll
          for (int nt = 0; nt < 4; nt++)
            bfr[nt] = *(const bf16x8_t*)&Bl[ch * 1024 + (wn * 64 + nt * 16 + l15) * 8];
#pragma unroll
          for (int mt = 0; mt < 4; mt++)
#pragma unroll
            for (int nt = 0; nt < 4; nt++)
              acc[mt][nt] = __builtin_amdgcn_mfma_f32_16x16x32_bf16(af[mt], bfr[nt], acc[mt][nt], 0, 0, 0);
        }
        __syncthreads();                       // reads done; B(ks+1) landed
        if (ks < 3) {
          writeA(areg);
          __syncthreads();                     // publish A(ks+1)
        }
      }

      // epilogue: v-scale + soft-threshold both pods (reg parity = pod)
#pragma unroll
      for (int nt = 0; nt < 4; nt++) {
        int posl = wn * 64 + nt * 16 + l15;
        int pos = n0 + posl;
        float v0 = vv[pos], v1 = vv[4096 + pos];
        float t0 = TT[pos], t1 = TT[4096 + pos];
#pragma unroll
        for (int mt = 0; mt < 4; mt++)
#pragma unroll
          for (int rp = 0; rp < 2; rp++) {
            int ol = wm * 32 + mt * 8 + quad * 2 + rp;   // 0..127
            float z0 = acc[mt][nt][rp * 2 + 0] * v0;
            float z1 = acc[mt][nt][rp * 2 + 1] * v1;
            float s0 = copysignf(fmaxf(fabsf(z0) - t0, 0.f), z0);
            float s1 = copysignf(fmaxf(fabsf(z1) - t1, 0.f), z1);
            smem[ol * 136 + posl] = f2bf(s0 + s1);
          }
      }
      __syncthreads();
      int o0 = m0 >> 1;                        // 0 or 128
#pragma unroll
      for (int i = 0; i < 4; i++) {
        int ci = i * 512 + tid;                // 2048 chunks = 128 rows x 16
        int row = ci >> 4, cc = ci & 15;
        u16x8_t vch = *(u16x8_t*)&smem[row * 136 + cc * 8];
        size_t img = (size_t)b * 256 + o0 + row;
        *(u16x8_t*)(obuf + img * 8192 + n0 + cc * 8) = vch;
      }
    }
  }

  gg.sync();                                   // f6 fully written, device-visible

  // ============ Phase 3: inverse 2D WHT + /4096 + x (R5 body, 4 units) ============
  {
    bf16x8_t hf[2][4];
#pragma unroll
    for (int kc = 0; kc < 2; kc++)
#pragma unroll
      for (int t = 0; t < 4; t++) {
        bf16x8_t h;
#pragma unroll
        for (int jj = 0; jj < 8; jj++) {
          int k = kc * 32 + quad * 8 + jj, n = t * 16 + l15;
          h[jj] = (__builtin_popcount(k & n) & 1) ? (__bf16)-1.0f : (__bf16)1.0f;
        }
        hf[kc][t] = h;
      }

    for (int j = 0; j < 4; ++j) {
      __syncthreads();                         // smem reuse between units
      int u = bid + j * 256;                   // 0..1023
      size_t img = (size_t)u * 8 + wave;       // 0..8191
      unsigned short* T1t = smem + wave * 4608;

#pragma unroll
      for (int l = 0; l < 8; l++) {
        int e = (l * 64 + lane) * 8;
        u16x8_t sv = *(const u16x8_t*)(obuf + img * 8192 + e);
        int row = e >> 6, col = e & 63;
        *(u16x8_t*)&T1t[row * 72 + col] = sv;
      }

      bf16x8_t fa[4][2];
#pragma unroll
      for (int mt = 0; mt < 4; mt++)
#pragma unroll
        for (int kc = 0; kc < 2; kc++)
          fa[mt][kc] = *(const bf16x8_t*)&T1t[(mt * 16 + l15) * 72 + kc * 32 + quad * 8];

      // GEMM1: U = f6*H, strip-mined; store transposed into T1t
#pragma unroll
      for (int nt = 0; nt < 4; nt++) {
        f32x4_t a1c[4];
#pragma unroll
        for (int mt = 0; mt < 4; mt++) a1c[mt] = (f32x4_t){0.f, 0.f, 0.f, 0.f};
#pragma unroll
        for (int kc = 0; kc < 2; kc++)
#pragma unroll
          for (int mt = 0; mt < 4; mt++)
            a1c[mt] = __builtin_amdgcn_mfma_f32_16x16x32_bf16(fa[mt][kc], hf[kc][nt], a1c[mt], 0, 0, 0);
#pragma unroll
        for (int mt = 0; mt < 4; mt++) {
          u16x4_t t4;
#pragma unroll
          for (int r = 0; r < 4; r++) t4[r] = f2bf_t(a1c[mt][r]);
          *(u16x4_t*)&T1t[(nt * 16 + l15) * 72 + mt * 16 + quad * 4] = t4;
        }
      }

      // GEMM2: V = H*U
      f32x4_t acc[4][4];
#pragma unroll
      for (int mt = 0; mt < 4; mt++)
#pragma unroll
        for (int nt = 0; nt < 4; nt++) acc[mt][nt] = (f32x4_t){0.f, 0.f, 0.f, 0.f};
#pragma unroll
      for (int kc = 0; kc < 2; kc++)
#pragma unroll
        for (int nt = 0; nt < 4; nt++) {
          bf16x8_t bfr = *(bf16x8_t*)&T1t[(nt * 16 + l15) * 72 + kc * 32 + quad * 8];
#pragma unroll
          for (int mt = 0; mt < 4; mt++)
            acc[mt][nt] = __builtin_amdgcn_mfma_f32_16x16x32_bf16(hf[kc][mt], bfr, acc[mt][nt], 0, 0, 0);
        }

      const float sc = 1.0f / 4096.0f;
#pragma unroll
      for (int mt = 0; mt < 4; mt++)
#pragma unroll
        for (int nt = 0; nt < 4; nt++)
#pragma unroll
          for (int r = 0; r < 4; r++)
            T1t[(mt * 16 + quad * 4 + r) * 72 + nt * 16 + l15] = f2bf(acc[mt][nt][r] * sc);

      float* outf = (float*)obuf;
      const float* xim = x + img * 4096;
#pragma unroll
      for (int l = 0; l < 8; l++) {
        int e = (l * 64 + lane) * 8;
        int row = e >> 6, col = e & 63;
        u16x8_t tv = *(u16x8_t*)&T1t[row * 72 + col];
        f32x4_t x0 = *(const f32x4_t*)(xim + e);
        f32x4_t x1 = *(const f32x4_t*)(xim + e + 4);
        f32x4_t o0, o1;
#pragma unroll
        for (int jj = 0; jj < 4; jj++) { o0[jj] = bf2f(tv[jj]) + x0[jj]; o1[jj] = bf2f(tv[4 + jj]) + x1[jj]; }
        *(f32x4_t*)(outf + img * 4096 + e) = o0;
        *(f32x4_t*)(outf + img * 4096 + e + 4) = o1;
      }
    }
  }
}

// ======================= fallback: proven R8 3-kernel path =======================

// block = 512 thr = 8 waves, wave -> image c = cg*8+wave; grid (32 cg, 32 b)
__global__ __launch_bounds__(512) void k_fwd(const float* __restrict__ x,
                                             unsigned short* __restrict__ obuf) {
  __shared__ unsigned short smem[36864];
  int tid = threadIdx.x;
  int lane = tid & 63, wave = tid >> 6;
  int quad = lane >> 4, l15 = lane & 15;
  int cg = blockIdx.x, b = blockIdx.y;
  size_t img = (size_t)b * 256 + cg * 8 + wave;
  unsigned short* T1t = smem + wave * 4608;

  const float* xim = x + img * 4096;
#pragma unroll
  for (int l = 0; l < 16; l++) {
    int e = (l * 64 + lane) * 4;
    f32x4_t sv = *(const f32x4_t*)(xim + e);
    u16x4_t u;
#pragma unroll
    for (int j = 0; j < 4; j++) u[j] = f2bf_t(sv[j]);
    int row = e >> 6, col = e & 63;
    *(u16x4_t*)&T1t[row * 72 + col] = u;
  }

  bf16x8_t hf[2][4];
#pragma unroll
  for (int kc = 0; kc < 2; kc++)
#pragma unroll
    for (int t = 0; t < 4; t++) {
      bf16x8_t h;
#pragma unroll
      for (int j = 0; j < 8; j++) {
        int k = kc * 32 + quad * 8 + j, n = t * 16 + l15;
        h[j] = (__builtin_popcount(k & n) & 1) ? (__bf16)-1.0f : (__bf16)1.0f;
      }
      hf[kc][t] = h;
    }

  bf16x8_t xa[4][2];
#pragma unroll
  for (int mt = 0; mt < 4; mt++)
#pragma unroll
    for (int kc = 0; kc < 2; kc++)
      xa[mt][kc] = *(const bf16x8_t*)&T1t[(mt * 16 + l15) * 72 + kc * 32 + quad * 8];

#pragma unroll
  for (int nt = 0; nt < 4; nt++) {
    f32x4_t a1c[4];
#pragma unroll
    for (int mt = 0; mt < 4; mt++) a1c[mt] = (f32x4_t){0.f, 0.f, 0.f, 0.f};
#pragma unroll
    for (int kc = 0; kc < 2; kc++)
#pragma unroll
      for (int mt = 0; mt < 4; mt++)
        a1c[mt] = __builtin_amdgcn_mfma_f32_16x16x32_bf16(xa[mt][kc], hf[kc][nt], a1c[mt], 0, 0, 0);
#pragma unroll
    for (int mt = 0; mt < 4; mt++) {
      u16x4_t t4;
#pragma unroll
      for (int r = 0; r < 4; r++) t4[r] = f2bf_t(a1c[mt][r]);
      *(u16x4_t*)&T1t[(nt * 16 + l15) * 72 + mt * 16 + quad * 4] = t4;
    }
  }

  f32x4_t acc[4][4];
#pragma unroll
  for (int mt = 0; mt < 4; mt++)
#pragma unroll
    for (int nt = 0; nt < 4; nt++) acc[mt][nt] = (f32x4_t){0.f, 0.f, 0.f, 0.f};
#pragma unroll
  for (int kc = 0; kc < 2; kc++)
#pragma unroll
    for (int nt = 0; nt < 4; nt++) {
      bf16x8_t bfr = *(bf16x8_t*)&T1t[(nt * 16 + l15) * 72 + kc * 32 + quad * 8];
#pragma unroll
      for (int mt = 0; mt < 4; mt++)
        acc[mt][nt] = __builtin_amdgcn_mfma_f32_16x16x32_bf16(hf[kc][mt], bfr, acc[mt][nt], 0, 0, 0);
    }

  __syncthreads();
#pragma unroll
  for (int mt = 0; mt < 4; mt++)
#pragma unroll
    for (int nt = 0; nt < 4; nt++)
#pragma unroll
      for (int r = 0; r < 4; r++) {
        int pos = (mt * 16 + quad * 4 + r) * 64 + nt * 16 + l15;
        smem[pos * 8 + (wave ^ (quad << 1))] = f2bf(acc[mt][nt][r]);
      }
  __syncthreads();
  size_t fbase = ((size_t)b * 32 + cg) * 4096;
  int hb = wave >> 2;
  if (hb) {
#pragma unroll
    for (int i = 0; i < 8; i++) {
      int pos = i * 512 + tid;
      u32x4_t c = *(u32x4_t*)&smem[pos * 8];
      const int q = (2 * i + 1) & 3;
      u32x4_t o;
      o[0] = c[0 ^ q]; o[1] = c[1 ^ q]; o[2] = c[2 ^ q]; o[3] = c[3 ^ q];
      *(u32x4_t*)(obuf + Faddr((fbase + pos) * 8)) = o;
    }
  } else {
#pragma unroll
    for (int i = 0; i < 8; i++) {
      int pos = i * 512 + tid;
      u32x4_t c = *(u32x4_t*)&smem[pos * 8];
      const int q = (2 * i) & 3;
      u32x4_t o;
      o[0] = c[0 ^ q]; o[1] = c[1 ^ q]; o[2] = c[2 ^ q]; o[3] = c[3 ^ q];
      *(u32x4_t*)(obuf + Faddr((fbase + pos) * 8)) = o;
    }
  }
}

// block = 256 thr = 4 waves; grid (32 n-tile, 4 m-tile, 32 b). 48 KiB LDS.
__global__ __launch_bounds__(256) void k_gemm(const float* __restrict__ Wf,
                                              const float* __restrict__ vv,
                                              const float* __restrict__ TT,
                                              unsigned short* __restrict__ obuf) {
  __shared__ unsigned short smem2[24576];
  unsigned short* Alds = smem2;
  int tid = threadIdx.x;
  int lane = tid & 63, wave = tid >> 6;
  int quad = lane >> 4, l15 = lane & 15;
  int wm = wave & 1, wn = wave >> 1;
  int n0 = blockIdx.x * 128;
  int m0 = blockIdx.y * 128;
  int b  = blockIdx.z;

  f32x4_t acc[4][4];
#pragma unroll
  for (int mt = 0; mt < 4; mt++)
#pragma unroll
    for (int nt = 0; nt < 4; nt++) acc[mt][nt] = (f32x4_t){0.f, 0.f, 0.f, 0.f};

  auto issueB = [&](int ks, int buf) {
    unsigned short* Bl = smem2 + 8192 + buf * 8192;
#pragma unroll
    for (int i = 0; i < 4; i++) {
      int idx = i * 256 + tid;
      int r = idx & 127, cch = idx >> 7;
      size_t f = (((size_t)b * 32 + ks * 8 + cch) * 4096 + n0 + r) * 8;
      const unsigned short* src = obuf + Faddr(f);
      __builtin_amdgcn_global_load_lds(
          (const __attribute__((address_space(1))) void*)src,
          (__attribute__((address_space(3))) void*)(Bl + idx * 8), 16, 0, 0);
    }
  };
  auto fetchA = [&](int ks, f32x4_t (&ar)[4][2]) {
    int k0 = ks * 64;
#pragma unroll
    for (int i = 0; i < 4; i++) {
      int idx = i * 256 + tid;
      int r = idx >> 3, cch = idx & 7;
      int gch = cch ^ (r & 7);
      int m = m0 + r;
      const float* wp = Wf + ((m & 1) << 16) + ((m >> 1) << 8) + k0 + gch * 8;
      ar[i][0] = *(const f32x4_t*)wp;
      ar[i][1] = *(const f32x4_t*)(wp + 4);
    }
  };
  auto writeA = [&](f32x4_t (&ar)[4][2]) {
#pragma unroll
    for (int i = 0; i < 4; i++) {
      int idx = i * 256 + tid;
      u16x8_t u;
#pragma unroll
      for (int j = 0; j < 4; j++) { u[j] = f2bf_t(ar[i][0][j]); u[4 + j] = f2bf_t(ar[i][1][j]); }
      *(u16x8_t*)&Alds[idx * 8] = u;
    }
  };

  f32x4_t areg[4][2];
  issueB(0, 0);
  fetchA(0, areg);
  writeA(areg);
  __syncthreads();

  for (int ks = 0; ks < 4; ++ks) {
    int p = ks & 1;
    if (ks < 3) {
      issueB(ks + 1, p ^ 1);
      fetchA(ks + 1, areg);
    }
    unsigned short* Bl = smem2 + 8192 + p * 8192;
#pragma unroll
    for (int kk = 0; kk < 2; ++kk) {
      bf16x8_t af[4], bfr[4];
#pragma unroll
      for (int mt = 0; mt < 4; mt++) {
        int row = wm * 64 + mt * 16 + l15;
        int s = (kk * 4 + quad) ^ (row & 7);
        af[mt] = *(const bf16x8_t*)&Alds[row * 64 + s * 8];
      }
      int ch = kk * 4 + quad;
#pragma unroll
      for (int nt = 0; nt < 4; nt++)
        bfr[nt] = *(const bf16x8_t*)&Bl[ch * 1024 + (wn * 64 + nt * 16 + l15) * 8];
#pragma unroll
      for (int mt = 0; mt < 4; mt++)
#pragma unroll
        for (int nt = 0; nt < 4; nt++)
          acc[mt][nt] = __builtin_amdgcn_mfma_f32_16x16x32_bf16(af[mt], bfr[nt], acc[mt][nt], 0, 0, 0);
    }
    __syncthreads();
    if (ks < 3) {
      writeA(areg);
      __syncthreads();
    }
  }

#pragma unroll
  for (int nt = 0; nt < 4; nt++) {
    int posl = wn * 64 + nt * 16 + l15;
    int pos = n0 + posl;
    float v0 = vv[pos], v1 = vv[4096 + pos];
    float t0 = TT[pos], t1 = TT[4096 + pos];
#pragma unroll
    for (int mt = 0; mt < 4; mt++)
#pragma unroll
      for (int rp = 0; rp < 2; rp++) {
        int ol = wm * 32 + mt * 8 + quad * 2 + rp;
        float z0 = acc[mt][nt][rp * 2 + 0] * v0;
        float z1 = acc[mt][nt][rp * 2 + 1] * v1;
        float s0 = copysignf(fmaxf(fabsf(z0) - t0, 0.f), z0);
        float s1 = copysignf(fmaxf(fabsf(z1) - t1, 0.f), z1);
        smem2[ol * 136 + posl] = f2bf(s0 + s1);
      }
  }
  __syncthreads();
  int o0 = m0 >> 1;
#pragma unroll
  for (int i = 0; i < 4; i++) {
    int ci = i * 256 + tid;
    int row = ci >> 4, cc = ci & 15;
    u16x8_t vch = *(u16x8_t*)&smem2[row * 136 + cc * 8];
    size_t img = (size_t)b * 256 + o0 + row;
    *(u16x8_t*)(obuf + img * 8192 + n0 + cc * 8) = vch;
  }
}

// block = 256 thr = 4 waves, wave -> image; grid 2048
__global__ __launch_bounds__(256) void k_inv(const float* __restrict__ x,
                                             unsigned short* __restrict__ obuf) {
  __shared__ unsigned short smem[18432];
  int tid = threadIdx.x;
  int lane = tid & 63, wave = tid >> 6;
  int quad = lane >> 4, l15 = lane & 15;
  size_t img = (size_t)blockIdx.x * 4 + wave;
  unsigned short* T1t = smem + wave * 4608;

#pragma unroll
  for (int l = 0; l < 8; l++) {
    int e = (l * 64 + lane) * 8;
    u16x8_t sv = *(const u16x8_t*)(obuf + img * 8192 + e);
    int row = e >> 6, col = e & 63;
    *(u16x8_t*)&T1t[row * 72 + col] = sv;
  }

  bf16x8_t hf[2][4];
#pragma unroll
  for (int kc = 0; kc < 2; kc++)
#pragma unroll
    for (int t = 0; t < 4; t++) {
      bf16x8_t h;
#pragma unroll
      for (int j = 0; j < 8; j++) {
        int k = kc * 32 + quad * 8 + j, n = t * 16 + l15;
        h[j] = (__builtin_popcount(k & n) & 1) ? (__bf16)-1.0f : (__bf16)1.0f;
      }
      hf[kc][t] = h;
    }

  bf16x8_t fa[4][2];
#pragma unroll
  for (int mt = 0; mt < 4; mt++)
#pragma unroll
    for (int kc = 0; kc < 2; kc++)
      fa[mt][kc] = *(const bf16x8_t*)&T1t[(mt * 16 + l15) * 72 + kc * 32 + quad * 8];

#pragma unroll
  for (int nt = 0; nt < 4; nt++) {
    f32x4_t a1c[4];
#pragma unroll
    for (int mt = 0; mt < 4; mt++) a1c[mt] = (f32x4_t){0.f, 0.f, 0.f, 0.f};
#pragma unroll
    for (int kc = 0; kc < 2; kc++)
#pragma unroll
      for (int mt = 0; mt < 4; mt++)
        a1c[mt] = __builtin_amdgcn_mfma_f32_16x16x32_bf16(fa[mt][kc], hf[kc][nt], a1c[mt], 0, 0, 0);
#pragma unroll
    for (int mt = 0; mt < 4; mt++) {
      u16x4_t t4;
#pragma unroll
      for (int r = 0; r < 4; r++) t4[r] = f2bf_t(a1c[mt][r]);
      *(u16x4_t*)&T1t[(nt * 16 + l15) * 72 + mt * 16 + quad * 4] = t4;
    }
  }

  f32x4_t acc[4][4];
#pragma unroll
  for (int mt = 0; mt < 4; mt++)
#pragma unroll
    for (int nt = 0; nt < 4; nt++) acc[mt][nt] = (f32x4_t){0.f, 0.f, 0.f, 0.f};
#pragma unroll
  for (int kc = 0; kc < 2; kc++)
#pragma unroll
    for (int nt = 0; nt < 4; nt++) {
      bf16x8_t bfr = *(bf16x8_t*)&T1t[(nt * 16 + l15) * 72 + kc * 32 + quad * 8];
#pragma unroll
      for (int mt = 0; mt < 4; mt++)
        acc[mt][nt] = __builtin_amdgcn_mfma_f32_16x16x32_bf16(hf[kc][mt], bfr, acc[mt][nt], 0, 0, 0);
    }

  const float sc = 1.0f / 4096.0f;
#pragma unroll
  for (int mt = 0; mt < 4; mt++)
#pragma unroll
    for (int nt = 0; nt < 4; nt++)
#pragma unroll
      for (int r = 0; r < 4; r++)
        T1t[(mt * 16 + quad * 4 + r) * 72 + nt * 16 + l15] = f2bf(acc[mt][nt][r] * sc);

  float* outf = (float*)obuf;
  const float* xim = x + img * 4096;
#pragma unroll
  for (int l = 0; l < 8; l++) {
    int e = (l * 64 + lane) * 8;
    int row = e >> 6, col = e & 63;
    u16x8_t tv = *(u16x8_t*)&T1t[row * 72 + col];
    f32x4_t x0 = *(const f32x4_t*)(xim + e);
    f32x4_t x1 = *(const f32x4_t*)(xim + e + 4);
    f32x4_t o0, o1;
#pragma unroll
    for (int j = 0; j < 4; j++) { o0[j] = bf2f(tv[j]) + x0[j]; o1[j] = bf2f(tv[4 + j]) + x1[j]; }
    *(f32x4_t*)(outf + img * 4096 + e) = o0;
    *(f32x4_t*)(outf + img * 4096 + e + 4) = o1;
  }
}

extern "C" void kernel_launch(void* const* d_in, const int* in_sizes, int n_in,
                              void* d_out, int out_size, void* d_ws, size_t ws_size,
                              hipStream_t stream) {
  const float* x = (const float*)d_in[0];      // (32,256,64,64) f32
  const float* v = (const float*)d_in[1];      // (2,64,64) f32
  const float* W = (const float*)d_in[2];      // (2,256,256) f32
  const float* T = (const float*)d_in[3];      // (2,64,64) f32
  unsigned short* obuf = (unsigned short*)d_out;
  (void)d_ws; (void)ws_size; (void)in_sizes; (void)n_in; (void)out_size;

  void* args[] = {(void*)&x, (void*)&W, (void*)&v, (void*)&T, (void*)&obuf};
  hipError_t e = hipLaunchCooperativeKernel((const void*)k_fused, dim3(256),
                                            dim3(512), args, 0, stream);
  if (e != hipSuccess) {
    // fallback: proven R8 3-kernel path (334 us measured)
    k_fwd<<<dim3(32, 32), 512, 0, stream>>>(x, obuf);
    k_gemm<<<dim3(32, 4, 32), 256, 0, stream>>>(W, v, T, obuf);
    k_inv<<<2048, 256, 0, stream>>>(x, obuf);
  }
}